// Round 1
// baseline (122.714 us; speedup 1.0000x reference)
//
#include <hip/hip_runtime.h>

// MeanTopKPooling2D: x [16,112,112,128] f32 -> out [16,110,110,128] f32
// out[b,oh,ow,c] = mean(top4 over q in [0,9) of x[b, i+p/3, j+p%3, c])
//   where P = q*12100 + oh*110 + ow; p = P%9; t = P/9; j = t%110; i = t/110
// (replicates the reference's flat-buffer reinterpreting reshape)

#define NH 110
#define NW 110
#define NC 128
#define IH 112
#define IW 112

__global__ __launch_bounds__(256) void meantopk_kernel(const float* __restrict__ x,
                                                       float* __restrict__ out,
                                                       int total4) {
    int tid = blockIdx.x * 256 + threadIdx.x;
    if (tid >= total4) return;

    unsigned c4  = tid & 31;        // 4-channel group: channels c4*4 .. c4*4+3
    unsigned pos = (unsigned)tid >> 5;  // b*12100 + oh*110 + ow
    unsigned ow  = pos % NW;
    unsigned tmp = pos / NW;
    unsigned oh  = tmp % NH;
    unsigned b   = tmp / NH;

    unsigned base = oh * NW + ow;
    const float* xb = x + (size_t)b * (IH * IW * NC) + c4 * 4u;

    float vals[9][4];
#pragma unroll
    for (int q = 0; q < 9; ++q) {
        unsigned P  = (unsigned)q * (NH * NW) + base;
        unsigned p  = P % 9u;
        unsigned t  = P / 9u;
        unsigned j  = t % NW;
        unsigned i  = t / NW;
        unsigned r  = i + p / 3u;
        unsigned cc = j + p % 3u;
        float4 f = *reinterpret_cast<const float4*>(xb + ((size_t)r * IW + cc) * NC);
        vals[q][0] = f.x; vals[q][1] = f.y; vals[q][2] = f.z; vals[q][3] = f.w;
    }

    float4 res;
    float* rp = reinterpret_cast<float*>(&res);
#pragma unroll
    for (int e = 0; e < 4; ++e) {
        float t0 = vals[0][e], t1 = vals[1][e], t2 = vals[2][e], t3 = vals[3][e];
#define CSWP(a, b) { float hi_ = fmaxf(a, b); float lo_ = fminf(a, b); (a) = hi_; (b) = lo_; }
        // sort first 4 descending (t0>=t1>=t2>=t3): 5-comparator network
        CSWP(t0, t1); CSWP(t2, t3); CSWP(t0, t2); CSWP(t1, t3); CSWP(t1, t2);
        // bubble-insert remaining 5 candidates
#pragma unroll
        for (int q = 4; q < 9; ++q) {
            float v = vals[q][e];
            CSWP(t0, v); CSWP(t1, v); CSWP(t2, v); CSWP(t3, v);
        }
#undef CSWP
        rp[e] = (t0 + t1 + t2 + t3) * 0.25f;
    }

    *reinterpret_cast<float4*>(out + (size_t)pos * NC + c4 * 4u) = res;
}

extern "C" void kernel_launch(void* const* d_in, const int* in_sizes, int n_in,
                              void* d_out, int out_size, void* d_ws, size_t ws_size,
                              hipStream_t stream) {
    const float* x = (const float*)d_in[0];
    float* out = (float*)d_out;

    const int total4 = 16 * NH * NW * (NC / 4);  // 6,195,200 threads
    const int blocks = (total4 + 255) / 256;
    meantopk_kernel<<<blocks, 256, 0, stream>>>(x, out, total4);
}

// Round 3
// 65.702 us; speedup vs baseline: 1.8678x; 1.8678x over previous
//
#include <hip/hip_runtime.h>

// MeanTopKPooling2D: x [16,112,112,128] f32 -> out [16,110,110,128] f32
// out[pos, c] = mean(top4 over q in [0,9) of x[b, pix(q, base)])
//   pos = b*12100 + base;  P = q*12100 + base;  p = P%9; t = P/9
//   pixel offset (r*112+cc) = t + 2*(t/110) + 112*(p/3) + (p%3)
//   with base = 9u+v:  t = q*1344 + u + (v+4q)/9 ;  p = (v+4q)%9   (12100 = 9*1344+4)
//
// 8 channels per thread: c8 = tid&15 (channels c8*8..c8*8+7), pos = tid>>4.
// Bijective XCD swizzle so co-reading blocks share an XCD L2; NT stores for
// the write-once output.

#define NH 110
#define NW 110
#define NC 128
#define IH 112
#define IW 112
#define NPOS (NH * NW)        // 12100
#define NWG 12100             // 16*12100*16 threads / 256

typedef float f32x4 __attribute__((ext_vector_type(4)));

__global__ __launch_bounds__(256) void meantopk_kernel(const float* __restrict__ x,
                                                       float* __restrict__ out) {
    // --- bijective XCD-aware block swizzle (nwg = 12100, nwg%8 = 4) ---
    const unsigned NX = 8u;
    unsigned bid = blockIdx.x;
    const unsigned qq = NWG / NX;        // 1512
    const unsigned rr = NWG % NX;        // 4
    unsigned xcd = bid % NX;
    unsigned idx = bid / NX;
    unsigned wg = (xcd < rr ? xcd * (qq + 1u)
                            : rr * (qq + 1u) + (xcd - rr) * qq) + idx;

    unsigned tid = wg * 256u + threadIdx.x;
    unsigned c8  = tid & 15u;            // channel-group of 8
    unsigned pos = tid >> 4;             // b*12100 + base
    unsigned base = pos % (unsigned)NPOS;
    unsigned b    = pos / (unsigned)NPOS;
    unsigned u = base / 9u;
    unsigned v = base % 9u;

    const float* xb = x + (size_t)b * (IH * IW * NC) + c8 * 8u;

    float va[9][8];
#pragma unroll
    for (int q = 0; q < 9; ++q) {
        unsigned w = v + 4u * (unsigned)q;            // < 41
        unsigned t = (unsigned)q * 1344u + u + w / 9u;
        unsigned p = w % 9u;
        unsigned pix = t + 2u * (t / 110u) + 112u * (p / 3u) + (p % 3u);
        const f32x4* src = reinterpret_cast<const f32x4*>(xb + (size_t)pix * NC);
        f32x4 f0 = src[0];
        f32x4 f1 = src[1];
        va[q][0] = f0.x; va[q][1] = f0.y; va[q][2] = f0.z; va[q][3] = f0.w;
        va[q][4] = f1.x; va[q][5] = f1.y; va[q][6] = f1.z; va[q][7] = f1.w;
    }

    float res[8];
#pragma unroll
    for (int e = 0; e < 8; ++e) {
        float a0 = va[0][e], a1 = va[1][e], a2 = va[2][e], a3 = va[3][e];
        float b0 = va[4][e], b1 = va[5][e], b2 = va[6][e], b3 = va[7][e];
        float v8 = va[8][e];
#define CSWP(p_, q_) { float hi_ = fmaxf(p_, q_); float lo_ = fminf(p_, q_); (p_) = hi_; (q_) = lo_; }
        // sort both quads descending (5 comparators each)
        CSWP(a0, a1); CSWP(a2, a3); CSWP(a0, a2); CSWP(a1, a3); CSWP(a1, a2);
        CSWP(b0, b1); CSWP(b2, b3); CSWP(b0, b2); CSWP(b1, b3); CSWP(b1, b2);
#undef CSWP
        // bitonic half-cleaner: top-4 multiset of the 8 (max side only)
        float m0 = fmaxf(a0, b3);
        float m1 = fmaxf(a1, b2);
        float m2 = fmaxf(a2, b1);
        float m3 = fmaxf(a3, b0);
        // top4 of {m0..m3, v8} = sum5 - min5
        float s  = m0 + m1 + m2 + m3 + v8;
        float mn = fminf(fminf(m0, m1), fminf(m2, m3));
        mn = fminf(mn, v8);
        res[e] = (s - mn) * 0.25f;
    }

    f32x4 r0 = {res[0], res[1], res[2], res[3]};
    f32x4 r1 = {res[4], res[5], res[6], res[7]};
    f32x4* op = reinterpret_cast<f32x4*>(out + (size_t)pos * NC + c8 * 8u);
    __builtin_nontemporal_store(r0, op);
    __builtin_nontemporal_store(r1, op + 1);
}

extern "C" void kernel_launch(void* const* d_in, const int* in_sizes, int n_in,
                              void* d_out, int out_size, void* d_ws, size_t ws_size,
                              hipStream_t stream) {
    const float* x = (const float*)d_in[0];
    float* out = (float*)d_out;
    meantopk_kernel<<<NWG, 256, 0, stream>>>(x, out);
}

// Round 4
// 51.074 us; speedup vs baseline: 2.4027x; 1.2864x over previous
//
#include <hip/hip_runtime.h>

// MeanTopKPooling2D: x [16,112,112,128] f32 -> out [16,110,110,128] f32
// out[pos, c] = mean(top4 over q in [0,9) of x[b, pix(q, base)])
//   pos = b*12100 + base;  P = q*12100 + base;  p = P%9; t = P/9
//   pixel offset (r*112+cc) = t + 2*(t/110) + 112*(p/3) + (p%3)
//   with base = 9u+v:  t = q*1344 + u + (v+4q)/9 ;  p = (v+4q)%9   (12100 = 9*1344+4)
//
// 8 channels per thread: c8 = tid&15 (channels c8*8..c8*8+7), pos = tid>>4.
// Bijective XCD swizzle so co-reading blocks share an XCD L2; NT stores for
// the write-once output. sched_barrier(0) after the load loop forces all 9
// loads in flight (R3: compiler folded merge into loads, VGPR=36 -> only ~4
// loads outstanding -> latency-bound at 65.7us).

#define NH 110
#define NW 110
#define NC 128
#define IH 112
#define IW 112
#define NPOS (NH * NW)        // 12100
#define NWG 12100             // 16*12100*16 threads / 256

typedef float f32x4 __attribute__((ext_vector_type(4)));

__global__ __launch_bounds__(256) void meantopk_kernel(const float* __restrict__ x,
                                                       float* __restrict__ out) {
    // --- bijective XCD-aware block swizzle (nwg = 12100, nwg%8 = 4) ---
    const unsigned NX = 8u;
    unsigned bid = blockIdx.x;
    const unsigned qq = NWG / NX;        // 1512
    const unsigned rr = NWG % NX;        // 4
    unsigned xcd = bid % NX;
    unsigned idx = bid / NX;
    unsigned wg = (xcd < rr ? xcd * (qq + 1u)
                            : rr * (qq + 1u) + (xcd - rr) * qq) + idx;

    unsigned tid = wg * 256u + threadIdx.x;
    unsigned c8  = tid & 15u;            // channel-group of 8
    unsigned pos = tid >> 4;             // b*12100 + base
    unsigned base = pos % (unsigned)NPOS;
    unsigned b    = pos / (unsigned)NPOS;
    unsigned u = base / 9u;
    unsigned v = base % 9u;

    const float* xb = x + (size_t)b * (IH * IW * NC) + c8 * 8u;

    float va[9][8];
#pragma unroll
    for (int q = 0; q < 9; ++q) {
        unsigned w = v + 4u * (unsigned)q;            // < 41
        unsigned t = (unsigned)q * 1344u + u + w / 9u;
        unsigned p = w % 9u;
        unsigned pix = t + 2u * (t / 110u) + 112u * (p / 3u) + (p % 3u);
        const f32x4* src = reinterpret_cast<const f32x4*>(xb + (size_t)pix * NC);
        f32x4 f0 = src[0];
        f32x4 f1 = src[1];
        va[q][0] = f0.x; va[q][1] = f0.y; va[q][2] = f0.z; va[q][3] = f0.w;
        va[q][4] = f1.x; va[q][5] = f1.y; va[q][6] = f1.z; va[q][7] = f1.w;
    }

    // Force all 9 loads issued before the merge network consumes anything:
    // compiler then emits graduated vmcnt(N) waits -> 9-deep load pipeline.
    __builtin_amdgcn_sched_barrier(0);

    float res[8];
#pragma unroll
    for (int e = 0; e < 8; ++e) {
        float a0 = va[0][e], a1 = va[1][e], a2 = va[2][e], a3 = va[3][e];
        float b0 = va[4][e], b1 = va[5][e], b2 = va[6][e], b3 = va[7][e];
        float v8 = va[8][e];
#define CSWP(p_, q_) { float hi_ = fmaxf(p_, q_); float lo_ = fminf(p_, q_); (p_) = hi_; (q_) = lo_; }
        // sort both quads descending (5 comparators each)
        CSWP(a0, a1); CSWP(a2, a3); CSWP(a0, a2); CSWP(a1, a3); CSWP(a1, a2);
        CSWP(b0, b1); CSWP(b2, b3); CSWP(b0, b2); CSWP(b1, b3); CSWP(b1, b2);
#undef CSWP
        // bitonic half-cleaner: top-4 multiset of the 8 (max side only)
        float m0 = fmaxf(a0, b3);
        float m1 = fmaxf(a1, b2);
        float m2 = fmaxf(a2, b1);
        float m3 = fmaxf(a3, b0);
        // top4 of {m0..m3, v8} = sum5 - min5
        float s  = m0 + m1 + m2 + m3 + v8;
        float mn = fminf(fminf(m0, m1), fminf(m2, m3));
        mn = fminf(mn, v8);
        res[e] = (s - mn) * 0.25f;
    }

    f32x4 r0 = {res[0], res[1], res[2], res[3]};
    f32x4 r1 = {res[4], res[5], res[6], res[7]};
    f32x4* op = reinterpret_cast<f32x4*>(out + (size_t)pos * NC + c8 * 8u);
    __builtin_nontemporal_store(r0, op);
    __builtin_nontemporal_store(r1, op + 1);
}

extern "C" void kernel_launch(void* const* d_in, const int* in_sizes, int n_in,
                              void* d_out, int out_size, void* d_ws, size_t ws_size,
                              hipStream_t stream) {
    const float* x = (const float*)d_in[0];
    float* out = (float*)d_out;
    meantopk_kernel<<<NWG, 256, 0, stream>>>(x, out);
}